// Round 11
// baseline (302.120 us; speedup 1.0000x reference)
//
#include <hip/hip_runtime.h>
#include <hip/hip_bf16.h>
#include <math.h>

typedef __hip_bfloat16 bf16;

// ---------------- problem constants ----------------
#define LSEQ 4096
#define DI 128
#define NSTATE 16
#define NK 4
#define NCHUNK 128     // chunks of 32 positions
#define CLEN 32
#define NGRP 8         // two-level combine: 8 groups of 16 chunks
#define CHTOT 16384    // 2 scans * 4 k * 128 d * 16 n

// ---------------- fp32 input staging (packed, converted once per call) ----------------
#define IN_X0    0
#define IN_X1    262144
#define IN_IPW0  524288
#define IN_IPW1  540672
#define IN_CW0   557056
#define IN_CB0   558208
#define IN_CW1   558336
#define IN_CB1   559488
#define IN_XPW0  559616
#define IN_DTW0  578048
#define IN_DTW1  580096
#define IN_DTB0  582144
#define IN_DTB1  582656
#define IN_AL0   583168
#define IN_AL1   591360
#define IN_DS0   599552
#define IN_DS1   600064
#define IN_G0    600576
#define IN_B0    600704
#define IN_G1    600832
#define IN_B1    600960
#define IN_WO0   601088
#define IN_WO1   609280
#define END_IN   617472

// ---------------- intermediate buffers ----------------
// XCO0, XCO1, XT0, XT1 MUST be consecutive (scan plane selector uses +2*DI*LSEQ).
#define OFF_XI0  END_IN
#define OFF_XI1  (OFF_XI0 + DI*LSEQ)
#define OFF_XCO0 (OFF_XI1 + DI*LSEQ)
#define OFF_XCO1 (OFF_XCO0 + DI*LSEQ)
#define OFF_XT0  (OFF_XCO1 + DI*LSEQ)
#define OFF_XT1  (OFF_XT0 + DI*LSEQ)
#define OFF_SZ0  (OFF_XT1 + DI*LSEQ)
#define OFF_SZ1  (OFF_SZ0 + LSEQ*DI)
#define OFF_XDBL (OFF_SZ1 + LSEQ*DI)        // [k][36][l]: rows 0-3 dtr, 4-19 B, 20-35 C
#define OFF_CHP  (OFF_XDBL + NK*36*LSEQ)    // per-chunk decay; after comb_a: within-group prefix-prod Q
#define OFF_CHS  (OFF_CHP + NCHUNK*CHTOT)   // per-chunk sum;   after comb_a: within-group local h-init
#define OFF_GP   (OFF_CHS + NCHUNK*CHTOT)   // group aggregate decay
#define OFF_GS   (OFF_GP + NGRP*CHTOT)      // group aggregate sum
#define OFF_GH   (OFF_GS + NGRP*CHTOT)      // group-start h
#define OFF_OY   (OFF_GH + NGRP*CHTOT)      // per-direction scan out, [s][k][l][d]
#define WS_FLOATS (OFF_OY + 2*NK*LSEQ*DI)

__device__ __forceinline__ float softplus_f(float x) {
  return x > 20.f ? x : __logf(1.f + __expf(x));
}
__device__ __forceinline__ float silu_f(float x) {
  return x / (1.f + __expf(-x));
}
// inline dtype probe: wave 0 samples even bf16 indices of in_proj0_w.
__device__ __forceinline__ int probe_f32(const void* probe, int t, int* sh) {
  if (t < 64) {
    int idx = 2 * ((t * 127) & 4095);
    float v = __bfloat162float(((const bf16*)probe)[idx]);
    int weird = (!(v == v)) || (fabsf(v) > 4.0f);
    unsigned long long m = __ballot(weird);
    if (t == 0) *sh = (__popcll(m) >= 8) ? 1 : 0;
  }
  __syncthreads();
  return *sh;
}

struct Ptrs { const void* p[23]; };
__constant__ const int g_cnt[23] = {262144, 262144, 16384, 16384, 1152, 128, 1152, 128,
                                    18432, 2048, 2048, 512, 512, 8192, 8192, 512, 512,
                                    128, 128, 128, 128, 8192, 8192};
__constant__ const int g_dst[23] = {IN_X0, IN_X1, IN_IPW0, IN_IPW1, IN_CW0, IN_CB0,
                                    IN_CW1, IN_CB1, IN_XPW0, IN_DTW0, IN_DTW1, IN_DTB0,
                                    IN_DTB1, IN_AL0, IN_AL1, IN_DS0, IN_DS1, IN_G0,
                                    IN_B0, IN_G1, IN_B1, IN_WO0, IN_WO1};

// ---------------- K0: convert inputs to fp32 staging ----------------
__global__ __launch_bounds__(256) void k_convert(Ptrs pt, const void* probe,
                                                 float* __restrict__ ws) {
  __shared__ int sf32;
  int t = threadIdx.x;
  int f32 = probe_f32(probe, t, &sf32);
  int gid = blockIdx.x * 256 + t;
  if (gid < END_IN) {
    int j = 0;
#pragma unroll
    for (int q = 0; q < 22; q++)
      if (gid >= g_dst[q] + g_cnt[q]) j = q + 1;
    int off = gid - g_dst[j];
    float v;
    if (f32) v = ((const float*)pt.p[j])[off];
    else v = __bfloat162float(((const bf16*)pt.p[j])[off]);
    ws[gid] = v;
  }
}

// ---------------- K1: in_proj (x @ W^T), split xi / silu(z); 16-l tiles ----------------
// 16-l per thread -> xi stores are full contiguous 64B per thread (no partial lines).
__global__ __launch_bounds__(256) void k_inproj(float* __restrict__ ws) {
  int b = blockIdx.y;
  const float* __restrict__ x = ws + (b ? IN_X1 : IN_X0);
  const float* __restrict__ w = ws + (b ? IN_IPW1 : IN_IPW0);
  float* xi = ws + (b ? OFF_XI1 : OFF_XI0);
  float* sz = ws + (b ? OFF_SZ1 : OFF_SZ0);
  int l0 = blockIdx.x * 16;
  int j = threadIdx.x;  // output channel 0..255
  float acc[16];
#pragma unroll
  for (int p = 0; p < 16; p++) acc[p] = 0.f;
  for (int cc = 0; cc < 4; cc++) {
    float wr[16];
#pragma unroll
    for (int c = 0; c < 16; c++) wr[c] = w[j * 64 + cc * 16 + c];
#pragma unroll
    for (int p = 0; p < 16; p++) {
      const float* xr = x + (l0 + p) * 64 + cc * 16;  // uniform -> scalar loads
#pragma unroll
      for (int c = 0; c < 16; c++) acc[p] += xr[c] * wr[c];
    }
  }
  if (j < 128) {
#pragma unroll
    for (int p = 0; p < 16; p++) xi[j * LSEQ + l0 + p] = acc[p];
  } else {
    int d = j - 128;
#pragma unroll
    for (int p = 0; p < 16; p++) sz[(l0 + p) * 128 + d] = silu_f(acc[p]);
  }
}

// ---------------- K2: depthwise 3x3 conv + SiLU; 16-row strips, 1024 blocks ----------------
__global__ __launch_bounds__(256) void k_conv(float* __restrict__ ws) {
  int d = blockIdx.x, b = blockIdx.y, hq = blockIdx.z;
  const float* cw = ws + (b ? IN_CW1 : IN_CW0) + d * 9;
  float bias = (ws + (b ? IN_CB1 : IN_CB0))[d];
  const float* xin = ws + (b ? OFF_XI1 : OFF_XI0) + d * LSEQ;
  float* xo = ws + (b ? OFF_XCO1 : OFF_XCO0) + d * LSEQ;
  float* xt = ws + (b ? OFF_XT1 : OFF_XT0) + d * LSEQ;
  float wreg[9];
#pragma unroll
  for (int i = 0; i < 9; i++) wreg[i] = cw[i];
  __shared__ float pl[18 * 64];
  __shared__ float po[64 * 17];
  int h0 = hq * 16;
  for (int i = threadIdx.x; i < 18 * 64; i += 256) {
    int r = i >> 6, w = i & 63;
    int h = h0 + r - 1;
    pl[i] = (h >= 0 && h < 64) ? xin[h * 64 + w] : 0.f;
  }
  __syncthreads();
  for (int i = threadIdx.x; i < 1024; i += 256) {
    int hl = i >> 6, w = i & 63;
    float a = bias;
#pragma unroll
    for (int kh = 0; kh < 3; kh++) {
      int pr = hl + kh;
#pragma unroll
      for (int kw = 0; kw < 3; kw++) {
        int ww = w + kw - 1;
        if (ww < 0 || ww > 63) continue;
        a += pl[pr * 64 + ww] * wreg[kh * 3 + kw];
      }
    }
    float r = silu_f(a);
    xo[(h0 + hl) * 64 + w] = r;
    po[w * 17 + hl] = r;
  }
  __syncthreads();
  for (int i = threadIdx.x; i < 1024; i += 256) {
    int w = i >> 4, hl = i & 15;
    xt[w * 64 + h0 + hl] = po[w * 17 + hl];
  }
}

// ---------------- scan kernels ----------------
// 256 threads = (s = t>>7, d = t&127); block = one 32-position chunk of one k.
// Chunk-summary layout: [chunk][(s,k)*16+n][d] -> per-n stores/loads are 4B/lane
// wave-contiguous (256B segments), eliminating the 64B-stride partial-line scatter.
// comb kernels treat chains as an opaque linear index -> layout-agnostic.
// Fast path: A[n] = (n+1)*A[0] => exp(de*A[n]) = e1^(n+1), 4 interleaved chains.

// ---------------- K3: scan pass 1 — x_dbl GEMV + per-chunk (P, S) ----------------
__global__ __launch_bounds__(256, 2) void k_scanA(float* __restrict__ ws) {
  int c = blockIdx.x, k = blockIdx.y;
  int t = threadIdx.x;
  int s = t >> 7, d = t & 127;
  __shared__ __align__(16) float xs0t[32 * 132];  // [tm][d], physical order
  __shared__ __align__(16) float xs1t[32 * 132];
  __shared__ __align__(16) float Wt[36 * 128];
  __shared__ float dtr[4 * 32];                   // [r][lm], logical order
  __shared__ __align__(16) float Bt[32 * 20];     // [lm][n]
  const float* alog = ws + (s ? IN_AL0 : IN_AL1);
  const float* dtw = ws + (s ? IN_DTW0 : IN_DTW1);
  const float* dtb = ws + (s ? IN_DTB0 : IN_DTB1);
  int rev = (k >= 2);
  int l0 = c * CLEN;
  int pbase = rev ? (4064 - l0) : l0;   // physical start of the 32-wide window
  int koff = (k & 1) ? 2 * DI * LSEQ : 0;
  const float* p0 = ws + OFF_XCO0 + koff;  // branch-0 plane (GEMV input + s=0 u)
  const float* p1 = ws + OFF_XCO1 + koff;  // branch-1 plane (s=1 u)
  // ---- stage plane tiles (coalesced) + W ----
  for (int i = t; i < 4096; i += 256) {
    int dd = i >> 5, m = i & 31;
    xs0t[m * 132 + dd] = p0[dd * LSEQ + pbase + m];
    xs1t[m * 132 + dd] = p1[dd * LSEQ + pbase + m];
  }
  const float* __restrict__ xpw = ws + IN_XPW0 + k * 4608;
  for (int i = t; i < 4608; i += 256) Wt[i] = xpw[i];
  // per-thread scan params (issue early)
  float A[NSTATE];
#pragma unroll
  for (int n = 0; n < NSTATE; n++) A[n] = -__expf(alog[(k * DI + d) * NSTATE + n]);
  bool fast = true;
#pragma unroll
  for (int n = 1; n < NSTATE; n++)
    fast = fast && (fabsf(A[n] - (float)(n + 1) * A[0]) <= 1e-3f * fabsf(A[n]));
  float4 wrv = *(const float4*)&dtw[(k * DI + d) * 4];
  float dbias = dtb[k * DI + d];
  __syncthreads();
  // ---- in-block x_dbl GEMV: 36 c x 32 l outputs ----
  float* xd = ws + OFF_XDBL + k * 36 * LSEQ;
  for (int idx = t; idx < 1152; idx += 256) {
    int cc = idx >> 5, lm = idx & 31;
    int tm = rev ? (31 - lm) : lm;
    const float* xr = &xs0t[tm * 132];
    const float* wr = &Wt[cc * 128];
    float acc = 0.f;
#pragma unroll
    for (int q = 0; q < 32; q++) {
      float4 x4 = *(const float4*)&xr[4 * q];
      float4 w4 = *(const float4*)&wr[4 * q];
      acc += x4.x * w4.x + x4.y * w4.y + x4.z * w4.z + x4.w * w4.w;
    }
    xd[cc * LSEQ + l0 + lm] = acc;       // for scanB
    if (cc < 4) dtr[cc * 32 + lm] = acc; // keep dt rows
    else if (cc < 20) Bt[lm * 20 + (cc - 4)] = acc;  // keep B rows
  }
  __syncthreads();
  // ---- local scan ----
  const float* myxs = s ? xs1t : xs0t;
  float h[NSTATE];
#pragma unroll
  for (int n = 0; n < NSTATE; n++) h[n] = 0.f;
  float sde = 0.f;
#pragma unroll
  for (int jj = 0; jj < 32; jj++) {
    float de = softplus_f(dtr[jj] * wrv.x + dtr[32 + jj] * wrv.y +
                          dtr[64 + jj] * wrv.z + dtr[96 + jj] * wrv.w + dbias);
    sde += de;
    int tm = rev ? (31 - jj) : jj;
    float u = myxs[tm * 132 + d];
    float duj = de * u;
    float4 b0 = *(const float4*)&Bt[jj * 20 + 0];
    float4 b1 = *(const float4*)&Bt[jj * 20 + 4];
    float4 b2 = *(const float4*)&Bt[jj * 20 + 8];
    float4 b3 = *(const float4*)&Bt[jj * 20 + 12];
    float bv[16] = {b0.x, b0.y, b0.z, b0.w, b1.x, b1.y, b1.z, b1.w,
                    b2.x, b2.y, b2.z, b2.w, b3.x, b3.y, b3.z, b3.w};
    if (fast) {
      float e1 = __expf(de * A[0]);
      float e2 = e1 * e1, e4 = e2 * e2;
      float p0v = e1, p1v = e2, p2v = e2 * e1, p3v = e4;
#pragma unroll
      for (int n = 0; n < NSTATE; n += 4) {
        h[n] = p0v * h[n] + duj * bv[n];
        h[n + 1] = p1v * h[n + 1] + duj * bv[n + 1];
        h[n + 2] = p2v * h[n + 2] + duj * bv[n + 2];
        h[n + 3] = p3v * h[n + 3] + duj * bv[n + 3];
        p0v *= e4; p1v *= e4; p2v *= e4; p3v *= e4;
      }
    } else {
#pragma unroll
      for (int n = 0; n < NSTATE; n++) {
        float da = __expf(de * A[n]);
        h[n] = da * h[n] + duj * bv[n];
      }
    }
  }
  // coalesced summary store: [(s,k)*16+n][d], 4B/lane contiguous per n
  int base2 = ((s * 4 + k) * NSTATE) * DI + d;
  float* Pp = ws + OFF_CHP + c * CHTOT + base2;
  float* Sp = ws + OFF_CHS + c * CHTOT + base2;
#pragma unroll
  for (int n = 0; n < NSTATE; n++) {
    Pp[n * DI] = __expf(A[n] * sde);
    Sp[n * DI] = h[n];
  }
}

// ---------------- K4b-1: within-group prefix (16 chunks each, 8 groups) ----------------
__global__ __launch_bounds__(256) void k_comb_a(float* __restrict__ ws) {
  int u = blockIdx.x * 256 + threadIdx.x;   // 0..131071
  int chain = u & (CHTOT - 1);
  int g = u >> 14;                          // 0..7
  float* P = ws + OFF_CHP + chain;
  float* S = ws + OFF_CHS + chain;
  int cb = g * 16;
  float h = 0.f, q = 1.f;
  for (int gg = 0; gg < 16; gg += 8) {
    float p[8], sv[8];
#pragma unroll
    for (int i = 0; i < 8; i++) {
      p[i] = P[(cb + gg + i) * CHTOT];
      sv[i] = S[(cb + gg + i) * CHTOT];
    }
#pragma unroll
    for (int i = 0; i < 8; i++) {
      P[(cb + gg + i) * CHTOT] = q;
      S[(cb + gg + i) * CHTOT] = h;
      h = p[i] * h + sv[i];
      q *= p[i];
    }
  }
  ws[OFF_GP + g * CHTOT + chain] = q;
  ws[OFF_GS + g * CHTOT + chain] = h;
}

// ---------------- K4b-2: across-group scan (8 groups) ----------------
__global__ __launch_bounds__(256) void k_comb_b(float* __restrict__ ws) {
  int chain = blockIdx.x * 256 + threadIdx.x;  // 0..16383
  float hg = 0.f;
  float p[8], sv[8];
#pragma unroll
  for (int i = 0; i < 8; i++) {
    p[i] = ws[OFF_GP + i * CHTOT + chain];
    sv[i] = ws[OFF_GS + i * CHTOT + chain];
  }
#pragma unroll
  for (int i = 0; i < 8; i++) {
    ws[OFF_GH + i * CHTOT + chain] = hg;
    hg = p[i] * hg + sv[i];
  }
}

// ---------------- K5: scan pass 2 — recompute with composed init, store y+u*D ----------------
__global__ __launch_bounds__(256, 2) void k_scanB(float* __restrict__ ws) {
  int c = blockIdx.x, k = blockIdx.y;
  int t = threadIdx.x;
  int s = t >> 7, d = t & 127;
  __shared__ __align__(16) float xs0t[32 * 132];
  __shared__ __align__(16) float xs1t[32 * 132];
  __shared__ float dtr[4 * 32];
  __shared__ __align__(16) float Bt[32 * 20];
  __shared__ __align__(16) float Ct[32 * 20];
  const float* xd_dt = ws + OFF_XDBL + k * 36 * LSEQ;
  const float* Bb = ws + OFF_XDBL + (k * 36 + 4) * LSEQ;
  const float* Cb = ws + OFF_XDBL + (k * 36 + 20) * LSEQ;
  const float* alog = ws + (s ? IN_AL0 : IN_AL1);
  const float* dtw = ws + (s ? IN_DTW0 : IN_DTW1);
  const float* dtb = ws + (s ? IN_DTB0 : IN_DTB1);
  const float* Dvec = ws + (s ? IN_DS0 : IN_DS1);
  float* oyb = ws + OFF_OY + (s * NK + k) * (LSEQ * DI);
  int rev = (k >= 2);
  int l0 = c * CLEN;
  int pbase = rev ? (4064 - l0) : l0;
  int koff = (k & 1) ? 2 * DI * LSEQ : 0;
  const float* p0 = ws + OFF_XCO0 + koff;
  const float* p1 = ws + OFF_XCO1 + koff;
  for (int i = t; i < 4096; i += 256) {
    int dd = i >> 5, m = i & 31;
    xs0t[m * 132 + dd] = p0[dd * LSEQ + pbase + m];
    xs1t[m * 132 + dd] = p1[dd * LSEQ + pbase + m];
  }
  if (t < 128) dtr[t] = xd_dt[(t >> 5) * LSEQ + l0 + (t & 31)];
#pragma unroll
  for (int q = 0; q < 2; q++) {
    int i = t + q * 256;
    int n = i >> 5, j2 = i & 31;
    Bt[j2 * 20 + n] = Bb[n * LSEQ + l0 + j2];
    Ct[j2 * 20 + n] = Cb[n * LSEQ + l0 + j2];
  }
  float A[NSTATE];
#pragma unroll
  for (int n = 0; n < NSTATE; n++) A[n] = -__expf(alog[(k * DI + d) * NSTATE + n]);
  bool fast = true;
#pragma unroll
  for (int n = 1; n < NSTATE; n++)
    fast = fast && (fabsf(A[n] - (float)(n + 1) * A[0]) <= 1e-3f * fabsf(A[n]));
  float4 wrv = *(const float4*)&dtw[(k * DI + d) * 4];
  float dbias = dtb[k * DI + d];
  float Dv = Dvec[k * DI + d];
  // composed h-init: h = Q_c * Hg + h_loc  (coalesced [(s,k)*16+n][d] layout)
  int base2 = ((s * 4 + k) * NSTATE) * DI + d;
  const float* Qp = ws + OFF_CHP + c * CHTOT + base2;
  const float* Lp = ws + OFF_CHS + c * CHTOT + base2;
  const float* Gp = ws + OFF_GH + (c >> 4) * CHTOT + base2;
  float h[NSTATE];
#pragma unroll
  for (int n = 0; n < NSTATE; n++)
    h[n] = Qp[n * DI] * Gp[n * DI] + Lp[n * DI];
  __syncthreads();
  const float* myxs = s ? xs1t : xs0t;
#pragma unroll
  for (int jj = 0; jj < 32; jj++) {
    float de = softplus_f(dtr[jj] * wrv.x + dtr[32 + jj] * wrv.y +
                          dtr[64 + jj] * wrv.z + dtr[96 + jj] * wrv.w + dbias);
    int tm = rev ? (31 - jj) : jj;
    float u = myxs[tm * 132 + d];
    float duj = de * u;
    float4 b0 = *(const float4*)&Bt[jj * 20 + 0];
    float4 b1 = *(const float4*)&Bt[jj * 20 + 4];
    float4 b2 = *(const float4*)&Bt[jj * 20 + 8];
    float4 b3 = *(const float4*)&Bt[jj * 20 + 12];
    float bv[16] = {b0.x, b0.y, b0.z, b0.w, b1.x, b1.y, b1.z, b1.w,
                    b2.x, b2.y, b2.z, b2.w, b3.x, b3.y, b3.z, b3.w};
    float4 c0 = *(const float4*)&Ct[jj * 20 + 0];
    float4 c1 = *(const float4*)&Ct[jj * 20 + 4];
    float4 c2 = *(const float4*)&Ct[jj * 20 + 8];
    float4 c3 = *(const float4*)&Ct[jj * 20 + 12];
    float cv[16] = {c0.x, c0.y, c0.z, c0.w, c1.x, c1.y, c1.z, c1.w,
                    c2.x, c2.y, c2.z, c2.w, c3.x, c3.y, c3.z, c3.w};
    float y = 0.f;
    if (fast) {
      float e1 = __expf(de * A[0]);
      float e2 = e1 * e1, e4 = e2 * e2;
      float p0v = e1, p1v = e2, p2v = e2 * e1, p3v = e4;
#pragma unroll
      for (int n = 0; n < NSTATE; n += 4) {
        h[n] = p0v * h[n] + duj * bv[n];
        h[n + 1] = p1v * h[n + 1] + duj * bv[n + 1];
        h[n + 2] = p2v * h[n + 2] + duj * bv[n + 2];
        h[n + 3] = p3v * h[n + 3] + duj * bv[n + 3];
        y += h[n] * cv[n] + h[n + 1] * cv[n + 1] + h[n + 2] * cv[n + 2] +
             h[n + 3] * cv[n + 3];
        p0v *= e4; p1v *= e4; p2v *= e4; p3v *= e4;
      }
    } else {
#pragma unroll
      for (int n = 0; n < NSTATE; n++) {
        float da = __expf(de * A[n]);
        h[n] = da * h[n] + duj * bv[n];
        y += h[n] * cv[n];
      }
    }
    y += u * Dv;
    oyb[(l0 + jj) * DI + d] = y;  // coalesced store, no atomics
  }
}

// ---------------- K6: 4-dir gather + LayerNorm + gate + out_proj; 16-l tiles, 512 blocks ----------------
__global__ __launch_bounds__(256) void k_post(const float* __restrict__ ws,
                                              const void* probe,
                                              void* __restrict__ out) {
  int b = blockIdx.y;
  __shared__ int sf32;
  int t = threadIdx.x;
  int in_f32 = probe_f32(probe, t, &sf32);
  const float* oy = ws + OFF_OY + b * (NK * LSEQ * DI);
  const float* sz = ws + (b ? OFF_SZ1 : OFF_SZ0);
  const float* g = ws + (b ? IN_G1 : IN_G0);
  const float* be = ws + (b ? IN_B1 : IN_B0);
  const float* wo = ws + (b ? IN_WO1 : IN_WO0);
  __shared__ __align__(16) float yl[16 * 132];
  __shared__ float wl[64 * 129];
  for (int i = t; i < 8192; i += 256) wl[(i >> 7) * 129 + (i & 127)] = wo[i];
  // ---- phase A: per-wave LN+gate, no barriers ----
  int wv = t >> 6, lane = t & 63;
  int l0 = blockIdx.x * 16;
  float g1 = g[lane], g2 = g[lane + 64];
  float be1 = be[lane], be2 = be[lane + 64];
#pragma unroll
  for (int i = 0; i < 4; i++) {
    int r = wv + 4 * i;
    int l = l0 + r;
    int lt = ((l & 63) << 6) | (l >> 6);
    float v1 = oy[(0 * LSEQ + l) * DI + lane] + oy[(1 * LSEQ + lt) * DI + lane] +
               oy[(2 * LSEQ + (4095 - l)) * DI + lane] + oy[(3 * LSEQ + (4095 - lt)) * DI + lane];
    float v2 = oy[(0 * LSEQ + l) * DI + lane + 64] + oy[(1 * LSEQ + lt) * DI + lane + 64] +
               oy[(2 * LSEQ + (4095 - l)) * DI + lane + 64] +
               oy[(3 * LSEQ + (4095 - lt)) * DI + lane + 64];
    float s1 = v1 + v2, s2 = v1 * v1 + v2 * v2;
#pragma unroll
    for (int m = 1; m < 64; m <<= 1) {
      s1 += __shfl_xor(s1, m);
      s2 += __shfl_xor(s2, m);
    }
    float mean = s1 * (1.f / 128.f);
    float var = s2 * (1.f / 128.f) - mean * mean;
    float inv = rsqrtf(var + 1e-5f);
    float ya1 = ((v1 - mean) * inv * g1 + be1) * sz[l * 128 + lane];
    float ya2 = ((v2 - mean) * inv * g2 + be2) * sz[l * 128 + lane + 64];
    yl[r * 132 + lane] = ya1;
    yl[r * 132 + lane + 64] = ya2;
  }
  __syncthreads();
  // ---- phase B: out GEMV, all 256 threads ----
  int m = t & 63, rg = t >> 6;
  float acc0 = 0.f, acc1 = 0.f, acc2 = 0.f, acc3 = 0.f;
  for (int q = 0; q < 32; q++) {
    float w0 = wl[m * 129 + 4 * q], w1 = wl[m * 129 + 4 * q + 1];
    float w2 = wl[m * 129 + 4 * q + 2], w3 = wl[m * 129 + 4 * q + 3];
    float4 y0 = *(const float4*)&yl[(rg + 0) * 132 + 4 * q];
    float4 y1 = *(const float4*)&yl[(rg + 4) * 132 + 4 * q];
    float4 y2 = *(const float4*)&yl[(rg + 8) * 132 + 4 * q];
    float4 y3 = *(const float4*)&yl[(rg + 12) * 132 + 4 * q];
    acc0 += y0.x * w0 + y0.y * w1 + y0.z * w2 + y0.w * w3;
    acc1 += y1.x * w0 + y1.y * w1 + y1.z * w2 + y1.w * w3;
    acc2 += y2.x * w0 + y2.y * w1 + y2.z * w2 + y2.w * w3;
    acc3 += y3.x * w0 + y3.y * w1 + y3.z * w2 + y3.w * w3;
  }
  float accs[4] = {acc0, acc1, acc2, acc3};
#pragma unroll
  for (int i = 0; i < 4; i++) {
    int l = l0 + rg + 4 * i;
    int oi = b * (LSEQ * 64) + l * 64 + m;
    if (in_f32) ((float*)out)[oi] = accs[i];
    else ((bf16*)out)[oi] = __float2bfloat16(accs[i]);
  }
}

extern "C" void kernel_launch(void* const* d_in, const int* in_sizes, int n_in,
                              void* d_out, int out_size, void* d_ws, size_t ws_size,
                              hipStream_t stream) {
  float* ws = (float*)d_ws;

  Ptrs pt;
  const int map[23] = {0, 1, 2, 3, 4, 5, 6, 7, 8, 10, 11, 12, 13, 14, 15, 16, 17,
                       18, 19, 20, 21, 22, 23};
  for (int j = 0; j < 23; j++) pt.p[j] = d_in[map[j]];
  const void* probe = d_in[2];

  k_convert<<<dim3((END_IN + 255) / 256), 256, 0, stream>>>(pt, probe, ws);
  k_inproj<<<dim3(LSEQ / 16, 2), 256, 0, stream>>>(ws);
  k_conv<<<dim3(DI, 2, 4), 256, 0, stream>>>(ws);
  k_scanA<<<dim3(NCHUNK, NK), 256, 0, stream>>>(ws);
  k_comb_a<<<dim3(NGRP * CHTOT / 256), 256, 0, stream>>>(ws);
  k_comb_b<<<dim3(CHTOT / 256), 256, 0, stream>>>(ws);
  k_scanB<<<dim3(NCHUNK, NK), 256, 0, stream>>>(ws);
  k_post<<<dim3(LSEQ / 16, 2), 256, 0, stream>>>(ws, probe, d_out);
}

// Round 12
// 202.516 us; speedup vs baseline: 1.4918x; 1.4918x over previous
//
#include <hip/hip_runtime.h>
#include <hip/hip_bf16.h>
#include <math.h>

typedef __hip_bfloat16 bf16;

// ---------------- problem constants ----------------
#define LSEQ 4096
#define DI 128
#define NSTATE 16
#define NK 4
#define NCHUNK 128     // chunks of 32 positions
#define CLEN 32
#define NGRP 8         // two-level combine: 8 groups of 16 chunks
#define CHTOT 16384    // 2 scans * 4 k * 128 d * 16 n

// ---------------- fp32 input staging (packed, converted once per call) ----------------
#define IN_X0    0
#define IN_X1    262144
#define IN_IPW0  524288
#define IN_IPW1  540672
#define IN_CW0   557056
#define IN_CB0   558208
#define IN_CW1   558336
#define IN_CB1   559488
#define IN_XPW0  559616
#define IN_DTW0  578048
#define IN_DTW1  580096
#define IN_DTB0  582144
#define IN_DTB1  582656
#define IN_AL0   583168
#define IN_AL1   591360
#define IN_DS0   599552
#define IN_DS1   600064
#define IN_G0    600576
#define IN_B0    600704
#define IN_G1    600832
#define IN_B1    600960
#define IN_WO0   601088
#define IN_WO1   609280
#define END_IN   617472

// ---------------- intermediate buffers ----------------
// XCO0, XCO1, XT0, XT1 MUST be consecutive (scan plane selector uses +2*DI*LSEQ).
#define OFF_XI0  END_IN
#define OFF_XI1  (OFF_XI0 + DI*LSEQ)
#define OFF_XCO0 (OFF_XI1 + DI*LSEQ)
#define OFF_XCO1 (OFF_XCO0 + DI*LSEQ)
#define OFF_XT0  (OFF_XCO1 + DI*LSEQ)
#define OFF_XT1  (OFF_XT0 + DI*LSEQ)
#define OFF_SZ0  (OFF_XT1 + DI*LSEQ)
#define OFF_SZ1  (OFF_SZ0 + LSEQ*DI)
#define OFF_XDBL (OFF_SZ1 + LSEQ*DI)        // [k][36][l]: rows 0-3 dtr, 4-19 B, 20-35 C
#define OFF_CHP  (OFF_XDBL + NK*36*LSEQ)    // per-chunk decay; after comb_a: within-group prefix-prod Q
#define OFF_CHS  (OFF_CHP + NCHUNK*CHTOT)   // per-chunk sum;   after comb_a: within-group local h-init
#define OFF_GP   (OFF_CHS + NCHUNK*CHTOT)   // group aggregate decay
#define OFF_GS   (OFF_GP + NGRP*CHTOT)      // group aggregate sum
#define OFF_GH   (OFF_GS + NGRP*CHTOT)      // group-start h
#define OFF_OY   (OFF_GH + NGRP*CHTOT)      // per-direction scan out, [s][k][l][d]
#define WS_FLOATS (OFF_OY + 2*NK*LSEQ*DI)

__device__ __forceinline__ float softplus_f(float x) {
  return x > 20.f ? x : __logf(1.f + __expf(x));
}
__device__ __forceinline__ float silu_f(float x) {
  return x / (1.f + __expf(-x));
}
// inline dtype probe: wave 0 samples even bf16 indices of in_proj0_w.
__device__ __forceinline__ int probe_f32(const void* probe, int t, int* sh) {
  if (t < 64) {
    int idx = 2 * ((t * 127) & 4095);
    float v = __bfloat162float(((const bf16*)probe)[idx]);
    int weird = (!(v == v)) || (fabsf(v) > 4.0f);
    unsigned long long m = __ballot(weird);
    if (t == 0) *sh = (__popcll(m) >= 8) ? 1 : 0;
  }
  __syncthreads();
  return *sh;
}

struct Ptrs { const void* p[23]; };
__constant__ const int g_cnt[23] = {262144, 262144, 16384, 16384, 1152, 128, 1152, 128,
                                    18432, 2048, 2048, 512, 512, 8192, 8192, 512, 512,
                                    128, 128, 128, 128, 8192, 8192};
__constant__ const int g_dst[23] = {IN_X0, IN_X1, IN_IPW0, IN_IPW1, IN_CW0, IN_CB0,
                                    IN_CW1, IN_CB1, IN_XPW0, IN_DTW0, IN_DTW1, IN_DTB0,
                                    IN_DTB1, IN_AL0, IN_AL1, IN_DS0, IN_DS1, IN_G0,
                                    IN_B0, IN_G1, IN_B1, IN_WO0, IN_WO1};

// ---------------- K0: convert inputs to fp32 staging ----------------
__global__ __launch_bounds__(256) void k_convert(Ptrs pt, const void* probe,
                                                 float* __restrict__ ws) {
  __shared__ int sf32;
  int t = threadIdx.x;
  int f32 = probe_f32(probe, t, &sf32);
  int gid = blockIdx.x * 256 + t;
  if (gid < END_IN) {
    int j = 0;
#pragma unroll
    for (int q = 0; q < 22; q++)
      if (gid >= g_dst[q] + g_cnt[q]) j = q + 1;
    int off = gid - g_dst[j];
    float v;
    if (f32) v = ((const float*)pt.p[j])[off];
    else v = __bfloat162float(((const bf16*)pt.p[j])[off]);
    ws[gid] = v;
  }
}

// ---------------- K1: in_proj (x @ W^T), split xi / silu(z); 8-l tiles, 1024 blocks ----------------
__global__ __launch_bounds__(256) void k_inproj(float* __restrict__ ws) {
  int b = blockIdx.y;
  const float* __restrict__ x = ws + (b ? IN_X1 : IN_X0);
  const float* __restrict__ w = ws + (b ? IN_IPW1 : IN_IPW0);
  float* xi = ws + (b ? OFF_XI1 : OFF_XI0);
  float* sz = ws + (b ? OFF_SZ1 : OFF_SZ0);
  int l0 = blockIdx.x * 8;
  int j = threadIdx.x;  // output channel 0..255
  float acc[8];
#pragma unroll
  for (int p = 0; p < 8; p++) acc[p] = 0.f;
  for (int cc = 0; cc < 4; cc++) {
    float wr[16];
#pragma unroll
    for (int c = 0; c < 16; c++) wr[c] = w[j * 64 + cc * 16 + c];
#pragma unroll
    for (int p = 0; p < 8; p++) {
      const float* xr = x + (l0 + p) * 64 + cc * 16;  // uniform -> scalar loads
#pragma unroll
      for (int c = 0; c < 16; c++) acc[p] += xr[c] * wr[c];
    }
  }
  if (j < 128) {
#pragma unroll
    for (int p = 0; p < 8; p++) xi[j * LSEQ + l0 + p] = acc[p];
  } else {
    int d = j - 128;
#pragma unroll
    for (int p = 0; p < 8; p++) sz[(l0 + p) * 128 + d] = silu_f(acc[p]);
  }
}

// ---------------- K2: depthwise 3x3 conv + SiLU; 16-row strips, 1024 blocks ----------------
__global__ __launch_bounds__(256) void k_conv(float* __restrict__ ws) {
  int d = blockIdx.x, b = blockIdx.y, hq = blockIdx.z;
  const float* cw = ws + (b ? IN_CW1 : IN_CW0) + d * 9;
  float bias = (ws + (b ? IN_CB1 : IN_CB0))[d];
  const float* xin = ws + (b ? OFF_XI1 : OFF_XI0) + d * LSEQ;
  float* xo = ws + (b ? OFF_XCO1 : OFF_XCO0) + d * LSEQ;
  float* xt = ws + (b ? OFF_XT1 : OFF_XT0) + d * LSEQ;
  float wreg[9];
#pragma unroll
  for (int i = 0; i < 9; i++) wreg[i] = cw[i];
  __shared__ float pl[18 * 64];
  __shared__ float po[64 * 17];
  int h0 = hq * 16;
  for (int i = threadIdx.x; i < 18 * 64; i += 256) {
    int r = i >> 6, w = i & 63;
    int h = h0 + r - 1;
    pl[i] = (h >= 0 && h < 64) ? xin[h * 64 + w] : 0.f;
  }
  __syncthreads();
  for (int i = threadIdx.x; i < 1024; i += 256) {
    int hl = i >> 6, w = i & 63;
    float a = bias;
#pragma unroll
    for (int kh = 0; kh < 3; kh++) {
      int pr = hl + kh;
#pragma unroll
      for (int kw = 0; kw < 3; kw++) {
        int ww = w + kw - 1;
        if (ww < 0 || ww > 63) continue;
        a += pl[pr * 64 + ww] * wreg[kh * 3 + kw];
      }
    }
    float r = silu_f(a);
    xo[(h0 + hl) * 64 + w] = r;
    po[w * 17 + hl] = r;
  }
  __syncthreads();
  for (int i = threadIdx.x; i < 1024; i += 256) {
    int w = i >> 4, hl = i & 15;
    xt[w * 64 + h0 + hl] = po[w * 17 + hl];
  }
}

// ---------------- scan kernels ----------------
// 256 threads = (s = t>>7, d = t&127); block = one 32-position chunk of one k.
// Both scans stage the two conv-plane tiles in LDS ([tile_pos][d], coalesced
// 128B staging loads, conflict-free broadcast u-reads). scanA additionally
// computes the x_dbl GEMV in-block from the SAME xs0 tile:
// x_dbl[k,c,l] = sum_d xs0[k,d,l]*W[k,c,d], written to global for scanB,
// dt/B rows kept in LDS for immediate use.
// Fast path: A[n] = (n+1)*A[0] => exp(de*A[n]) = e1^(n+1), 4 interleaved chains.

// ---------------- K3: scan pass 1 — x_dbl GEMV + per-chunk (P, S) ----------------
__global__ __launch_bounds__(256, 2) void k_scanA(float* __restrict__ ws) {
  int c = blockIdx.x, k = blockIdx.y;
  int t = threadIdx.x;
  int s = t >> 7, d = t & 127;
  __shared__ __align__(16) float xs0t[32 * 132];  // [tm][d], physical order
  __shared__ __align__(16) float xs1t[32 * 132];
  __shared__ __align__(16) float Wt[36 * 128];
  __shared__ float dtr[4 * 32];                   // [r][lm], logical order
  __shared__ __align__(16) float Bt[32 * 20];     // [lm][n]
  const float* alog = ws + (s ? IN_AL0 : IN_AL1);
  const float* dtw = ws + (s ? IN_DTW0 : IN_DTW1);
  const float* dtb = ws + (s ? IN_DTB0 : IN_DTB1);
  int rev = (k >= 2);
  int l0 = c * CLEN;
  int pbase = rev ? (4064 - l0) : l0;   // physical start of the 32-wide window
  int koff = (k & 1) ? 2 * DI * LSEQ : 0;
  const float* p0 = ws + OFF_XCO0 + koff;  // branch-0 plane (GEMV input + s=0 u)
  const float* p1 = ws + OFF_XCO1 + koff;  // branch-1 plane (s=1 u)
  // ---- stage plane tiles (coalesced) + W ----
  for (int i = t; i < 4096; i += 256) {
    int dd = i >> 5, m = i & 31;
    xs0t[m * 132 + dd] = p0[dd * LSEQ + pbase + m];
    xs1t[m * 132 + dd] = p1[dd * LSEQ + pbase + m];
  }
  const float* __restrict__ xpw = ws + IN_XPW0 + k * 4608;
  for (int i = t; i < 4608; i += 256) Wt[i] = xpw[i];
  // per-thread scan params (issue early)
  float A[NSTATE];
#pragma unroll
  for (int n = 0; n < NSTATE; n++) A[n] = -__expf(alog[(k * DI + d) * NSTATE + n]);
  bool fast = true;
#pragma unroll
  for (int n = 1; n < NSTATE; n++)
    fast = fast && (fabsf(A[n] - (float)(n + 1) * A[0]) <= 1e-3f * fabsf(A[n]));
  float4 wrv = *(const float4*)&dtw[(k * DI + d) * 4];
  float dbias = dtb[k * DI + d];
  __syncthreads();
  // ---- in-block x_dbl GEMV: 36 c x 32 l outputs ----
  float* xd = ws + OFF_XDBL + k * 36 * LSEQ;
  for (int idx = t; idx < 1152; idx += 256) {
    int cc = idx >> 5, lm = idx & 31;
    int tm = rev ? (31 - lm) : lm;
    const float* xr = &xs0t[tm * 132];
    const float* wr = &Wt[cc * 128];
    float acc = 0.f;
#pragma unroll
    for (int q = 0; q < 32; q++) {
      float4 x4 = *(const float4*)&xr[4 * q];
      float4 w4 = *(const float4*)&wr[4 * q];
      acc += x4.x * w4.x + x4.y * w4.y + x4.z * w4.z + x4.w * w4.w;
    }
    xd[cc * LSEQ + l0 + lm] = acc;       // for scanB
    if (cc < 4) dtr[cc * 32 + lm] = acc; // keep dt rows
    else if (cc < 20) Bt[lm * 20 + (cc - 4)] = acc;  // keep B rows
  }
  __syncthreads();
  // ---- local scan ----
  const float* myxs = s ? xs1t : xs0t;
  float h[NSTATE];
#pragma unroll
  for (int n = 0; n < NSTATE; n++) h[n] = 0.f;
  float sde = 0.f;
#pragma unroll
  for (int jj = 0; jj < 32; jj++) {
    float de = softplus_f(dtr[jj] * wrv.x + dtr[32 + jj] * wrv.y +
                          dtr[64 + jj] * wrv.z + dtr[96 + jj] * wrv.w + dbias);
    sde += de;
    int tm = rev ? (31 - jj) : jj;
    float u = myxs[tm * 132 + d];
    float duj = de * u;
    float4 b0 = *(const float4*)&Bt[jj * 20 + 0];
    float4 b1 = *(const float4*)&Bt[jj * 20 + 4];
    float4 b2 = *(const float4*)&Bt[jj * 20 + 8];
    float4 b3 = *(const float4*)&Bt[jj * 20 + 12];
    float bv[16] = {b0.x, b0.y, b0.z, b0.w, b1.x, b1.y, b1.z, b1.w,
                    b2.x, b2.y, b2.z, b2.w, b3.x, b3.y, b3.z, b3.w};
    if (fast) {
      float e1 = __expf(de * A[0]);
      float e2 = e1 * e1, e4 = e2 * e2;
      float p0v = e1, p1v = e2, p2v = e2 * e1, p3v = e4;
#pragma unroll
      for (int n = 0; n < NSTATE; n += 4) {
        h[n] = p0v * h[n] + duj * bv[n];
        h[n + 1] = p1v * h[n + 1] + duj * bv[n + 1];
        h[n + 2] = p2v * h[n + 2] + duj * bv[n + 2];
        h[n + 3] = p3v * h[n + 3] + duj * bv[n + 3];
        p0v *= e4; p1v *= e4; p2v *= e4; p3v *= e4;
      }
    } else {
#pragma unroll
      for (int n = 0; n < NSTATE; n++) {
        float da = __expf(de * A[n]);
        h[n] = da * h[n] + duj * bv[n];
      }
    }
  }
  int chainb = ((s * 4 + k) * DI + d) * NSTATE;
  float* Pp = ws + OFF_CHP + c * CHTOT + chainb;
  float* Sp = ws + OFF_CHS + c * CHTOT + chainb;
#pragma unroll
  for (int q = 0; q < 4; q++) {
    ((float4*)Pp)[q] = make_float4(__expf(A[4 * q] * sde), __expf(A[4 * q + 1] * sde),
                                   __expf(A[4 * q + 2] * sde), __expf(A[4 * q + 3] * sde));
    ((float4*)Sp)[q] = make_float4(h[4 * q], h[4 * q + 1], h[4 * q + 2], h[4 * q + 3]);
  }
}

// ---------------- K4b-1: within-group prefix (16 chunks each, 8 groups) ----------------
__global__ __launch_bounds__(256) void k_comb_a(float* __restrict__ ws) {
  int u = blockIdx.x * 256 + threadIdx.x;   // 0..131071
  int chain = u & (CHTOT - 1);
  int g = u >> 14;                          // 0..7
  float* P = ws + OFF_CHP + chain;
  float* S = ws + OFF_CHS + chain;
  int cb = g * 16;
  float h = 0.f, q = 1.f;
  for (int gg = 0; gg < 16; gg += 8) {
    float p[8], sv[8];
#pragma unroll
    for (int i = 0; i < 8; i++) {
      p[i] = P[(cb + gg + i) * CHTOT];
      sv[i] = S[(cb + gg + i) * CHTOT];
    }
#pragma unroll
    for (int i = 0; i < 8; i++) {
      P[(cb + gg + i) * CHTOT] = q;
      S[(cb + gg + i) * CHTOT] = h;
      h = p[i] * h + sv[i];
      q *= p[i];
    }
  }
  ws[OFF_GP + g * CHTOT + chain] = q;
  ws[OFF_GS + g * CHTOT + chain] = h;
}

// ---------------- K4b-2: across-group scan (8 groups) ----------------
__global__ __launch_bounds__(256) void k_comb_b(float* __restrict__ ws) {
  int chain = blockIdx.x * 256 + threadIdx.x;  // 0..16383
  float hg = 0.f;
  float p[8], sv[8];
#pragma unroll
  for (int i = 0; i < 8; i++) {
    p[i] = ws[OFF_GP + i * CHTOT + chain];
    sv[i] = ws[OFF_GS + i * CHTOT + chain];
  }
#pragma unroll
  for (int i = 0; i < 8; i++) {
    ws[OFF_GH + i * CHTOT + chain] = hg;
    hg = p[i] * hg + sv[i];
  }
}

// ---------------- K5: scan pass 2 — recompute with composed init, store y+u*D ----------------
__global__ __launch_bounds__(256, 2) void k_scanB(float* __restrict__ ws) {
  int c = blockIdx.x, k = blockIdx.y;
  int t = threadIdx.x;
  int s = t >> 7, d = t & 127;
  __shared__ __align__(16) float xs0t[32 * 132];
  __shared__ __align__(16) float xs1t[32 * 132];
  __shared__ float dtr[4 * 32];
  __shared__ __align__(16) float Bt[32 * 20];
  __shared__ __align__(16) float Ct[32 * 20];
  const float* xd_dt = ws + OFF_XDBL + k * 36 * LSEQ;
  const float* Bb = ws + OFF_XDBL + (k * 36 + 4) * LSEQ;
  const float* Cb = ws + OFF_XDBL + (k * 36 + 20) * LSEQ;
  const float* alog = ws + (s ? IN_AL0 : IN_AL1);
  const float* dtw = ws + (s ? IN_DTW0 : IN_DTW1);
  const float* dtb = ws + (s ? IN_DTB0 : IN_DTB1);
  const float* Dvec = ws + (s ? IN_DS0 : IN_DS1);
  float* oyb = ws + OFF_OY + (s * NK + k) * (LSEQ * DI);
  int rev = (k >= 2);
  int l0 = c * CLEN;
  int pbase = rev ? (4064 - l0) : l0;
  int koff = (k & 1) ? 2 * DI * LSEQ : 0;
  const float* p0 = ws + OFF_XCO0 + koff;
  const float* p1 = ws + OFF_XCO1 + koff;
  for (int i = t; i < 4096; i += 256) {
    int dd = i >> 5, m = i & 31;
    xs0t[m * 132 + dd] = p0[dd * LSEQ + pbase + m];
    xs1t[m * 132 + dd] = p1[dd * LSEQ + pbase + m];
  }
  if (t < 128) dtr[t] = xd_dt[(t >> 5) * LSEQ + l0 + (t & 31)];
#pragma unroll
  for (int q = 0; q < 2; q++) {
    int i = t + q * 256;
    int n = i >> 5, j2 = i & 31;
    Bt[j2 * 20 + n] = Bb[n * LSEQ + l0 + j2];
    Ct[j2 * 20 + n] = Cb[n * LSEQ + l0 + j2];
  }
  float A[NSTATE];
#pragma unroll
  for (int n = 0; n < NSTATE; n++) A[n] = -__expf(alog[(k * DI + d) * NSTATE + n]);
  bool fast = true;
#pragma unroll
  for (int n = 1; n < NSTATE; n++)
    fast = fast && (fabsf(A[n] - (float)(n + 1) * A[0]) <= 1e-3f * fabsf(A[n]));
  float4 wrv = *(const float4*)&dtw[(k * DI + d) * 4];
  float dbias = dtb[k * DI + d];
  float Dv = Dvec[k * DI + d];
  // composed h-init: h = Q_c * Hg + h_loc
  int chainb = ((s * 4 + k) * DI + d) * NSTATE;
  const float* Qp = ws + OFF_CHP + c * CHTOT + chainb;
  const float* Lp = ws + OFF_CHS + c * CHTOT + chainb;
  const float* Gp = ws + OFF_GH + (c >> 4) * CHTOT + chainb;
  float h[NSTATE];
#pragma unroll
  for (int q = 0; q < 4; q++) {
    float4 qv = ((const float4*)Qp)[q];
    float4 lv = ((const float4*)Lp)[q];
    float4 gv = ((const float4*)Gp)[q];
    h[4 * q] = qv.x * gv.x + lv.x;
    h[4 * q + 1] = qv.y * gv.y + lv.y;
    h[4 * q + 2] = qv.z * gv.z + lv.z;
    h[4 * q + 3] = qv.w * gv.w + lv.w;
  }
  __syncthreads();
  const float* myxs = s ? xs1t : xs0t;
#pragma unroll
  for (int jj = 0; jj < 32; jj++) {
    float de = softplus_f(dtr[jj] * wrv.x + dtr[32 + jj] * wrv.y +
                          dtr[64 + jj] * wrv.z + dtr[96 + jj] * wrv.w + dbias);
    int tm = rev ? (31 - jj) : jj;
    float u = myxs[tm * 132 + d];
    float duj = de * u;
    float4 b0 = *(const float4*)&Bt[jj * 20 + 0];
    float4 b1 = *(const float4*)&Bt[jj * 20 + 4];
    float4 b2 = *(const float4*)&Bt[jj * 20 + 8];
    float4 b3 = *(const float4*)&Bt[jj * 20 + 12];
    float bv[16] = {b0.x, b0.y, b0.z, b0.w, b1.x, b1.y, b1.z, b1.w,
                    b2.x, b2.y, b2.z, b2.w, b3.x, b3.y, b3.z, b3.w};
    float4 c0 = *(const float4*)&Ct[jj * 20 + 0];
    float4 c1 = *(const float4*)&Ct[jj * 20 + 4];
    float4 c2 = *(const float4*)&Ct[jj * 20 + 8];
    float4 c3 = *(const float4*)&Ct[jj * 20 + 12];
    float cv[16] = {c0.x, c0.y, c0.z, c0.w, c1.x, c1.y, c1.z, c1.w,
                    c2.x, c2.y, c2.z, c2.w, c3.x, c3.y, c3.z, c3.w};
    float y = 0.f;
    if (fast) {
      float e1 = __expf(de * A[0]);
      float e2 = e1 * e1, e4 = e2 * e2;
      float p0v = e1, p1v = e2, p2v = e2 * e1, p3v = e4;
#pragma unroll
      for (int n = 0; n < NSTATE; n += 4) {
        h[n] = p0v * h[n] + duj * bv[n];
        h[n + 1] = p1v * h[n + 1] + duj * bv[n + 1];
        h[n + 2] = p2v * h[n + 2] + duj * bv[n + 2];
        h[n + 3] = p3v * h[n + 3] + duj * bv[n + 3];
        y += h[n] * cv[n] + h[n + 1] * cv[n + 1] + h[n + 2] * cv[n + 2] +
             h[n + 3] * cv[n + 3];
        p0v *= e4; p1v *= e4; p2v *= e4; p3v *= e4;
      }
    } else {
#pragma unroll
      for (int n = 0; n < NSTATE; n++) {
        float da = __expf(de * A[n]);
        h[n] = da * h[n] + duj * bv[n];
        y += h[n] * cv[n];
      }
    }
    y += u * Dv;
    oyb[(l0 + jj) * DI + d] = y;  // coalesced store, no atomics
  }
}

// ---------------- K6: 4-dir gather + LayerNorm + gate + out_proj; 8-l tiles ----------------
__global__ __launch_bounds__(256) void k_post(const float* __restrict__ ws,
                                              const void* probe,
                                              void* __restrict__ out) {
  int b = blockIdx.y;
  __shared__ int sf32;
  int t = threadIdx.x;
  int in_f32 = probe_f32(probe, t, &sf32);
  const float* oy = ws + OFF_OY + b * (NK * LSEQ * DI);
  const float* sz = ws + (b ? OFF_SZ1 : OFF_SZ0);
  const float* g = ws + (b ? IN_G1 : IN_G0);
  const float* be = ws + (b ? IN_B1 : IN_B0);
  const float* wo = ws + (b ? IN_WO1 : IN_WO0);
  __shared__ __align__(16) float yl[8 * 132];
  __shared__ float wl[64 * 129];
  for (int i = t; i < 8192; i += 256) wl[(i >> 7) * 129 + (i & 127)] = wo[i];
  int wv = t >> 6, lane = t & 63;
  int l0 = blockIdx.x * 8;
  float g1 = g[lane], g2 = g[lane + 64];
  float be1 = be[lane], be2 = be[lane + 64];
#pragma unroll
  for (int i = 0; i < 2; i++) {
    int r = wv + 4 * i;
    int l = l0 + r;
    int ltr = ((l & 63) << 6) | (l >> 6);
    float v1 = oy[(0 * LSEQ + l) * DI + lane] + oy[(1 * LSEQ + ltr) * DI + lane] +
               oy[(2 * LSEQ + (4095 - l)) * DI + lane] + oy[(3 * LSEQ + (4095 - ltr)) * DI + lane];
    float v2 = oy[(0 * LSEQ + l) * DI + lane + 64] + oy[(1 * LSEQ + ltr) * DI + lane + 64] +
               oy[(2 * LSEQ + (4095 - l)) * DI + lane + 64] +
               oy[(3 * LSEQ + (4095 - ltr)) * DI + lane + 64];
    float s1 = v1 + v2, s2 = v1 * v1 + v2 * v2;
#pragma unroll
    for (int m = 1; m < 64; m <<= 1) {
      s1 += __shfl_xor(s1, m);
      s2 += __shfl_xor(s2, m);
    }
    float mean = s1 * (1.f / 128.f);
    float var = s2 * (1.f / 128.f) - mean * mean;
    float inv = rsqrtf(var + 1e-5f);
    float ya1 = ((v1 - mean) * inv * g1 + be1) * sz[l * 128 + lane];
    float ya2 = ((v2 - mean) * inv * g2 + be2) * sz[l * 128 + lane + 64];
    yl[r * 132 + lane] = ya1;
    yl[r * 132 + lane + 64] = ya2;
  }
  __syncthreads();
  int m = t & 63, rg = t >> 6;
  float acc0 = 0.f, acc1 = 0.f;
  for (int q = 0; q < 32; q++) {
    float w0 = wl[m * 129 + 4 * q], w1 = wl[m * 129 + 4 * q + 1];
    float w2 = wl[m * 129 + 4 * q + 2], w3 = wl[m * 129 + 4 * q + 3];
    float4 y0 = *(const float4*)&yl[(rg + 0) * 132 + 4 * q];
    float4 y1 = *(const float4*)&yl[(rg + 4) * 132 + 4 * q];
    acc0 += y0.x * w0 + y0.y * w1 + y0.z * w2 + y0.w * w3;
    acc1 += y1.x * w0 + y1.y * w1 + y1.z * w2 + y1.w * w3;
  }
  float accs[2] = {acc0, acc1};
#pragma unroll
  for (int i = 0; i < 2; i++) {
    int l = l0 + rg + 4 * i;
    int oi = b * (LSEQ * 64) + l * 64 + m;
    if (in_f32) ((float*)out)[oi] = accs[i];
    else ((bf16*)out)[oi] = __float2bfloat16(accs[i]);
  }
}

extern "C" void kernel_launch(void* const* d_in, const int* in_sizes, int n_in,
                              void* d_out, int out_size, void* d_ws, size_t ws_size,
                              hipStream_t stream) {
  float* ws = (float*)d_ws;

  Ptrs pt;
  const int map[23] = {0, 1, 2, 3, 4, 5, 6, 7, 8, 10, 11, 12, 13, 14, 15, 16, 17,
                       18, 19, 20, 21, 22, 23};
  for (int j = 0; j < 23; j++) pt.p[j] = d_in[map[j]];
  const void* probe = d_in[2];

  k_convert<<<dim3((END_IN + 255) / 256), 256, 0, stream>>>(pt, probe, ws);
  k_inproj<<<dim3(LSEQ / 8, 2), 256, 0, stream>>>(ws);
  k_conv<<<dim3(DI, 2, 4), 256, 0, stream>>>(ws);
  k_scanA<<<dim3(NCHUNK, NK), 256, 0, stream>>>(ws);
  k_comb_a<<<dim3(NGRP * CHTOT / 256), 256, 0, stream>>>(ws);
  k_comb_b<<<dim3(CHTOT / 256), 256, 0, stream>>>(ws);
  k_scanB<<<dim3(NCHUNK, NK), 256, 0, stream>>>(ws);
  k_post<<<dim3(LSEQ / 8, 2), 256, 0, stream>>>(ws, probe, d_out);
}